// Round 5
// baseline (331.824 us; speedup 1.0000x reference)
//
#include <hip/hip_runtime.h>
#include <hip/hip_bf16.h>

// Problem constants
#define BATCH 16
#define NH 8
#define NSEQ 1168          // 12*12 + 32*32
#define NPAD 1184          // NSEQ padded to multiple of 32
#define DH 32
#define DMODEL 256
#define MTOK (BATCH*NSEQ)  // 18688 = 146*128
#define LOG2E 1.4426950408889634f
#define QSCALE_L2 (0.17677669529663687f * 1.4426950408889634f)  // 32^-0.5 * log2e
#define NRELCAP 8448       // num_rel = 8196 expected

typedef __bf16 bf16_t;
typedef __bf16 bf16x8 __attribute__((ext_vector_type(8)));
typedef __bf16 bf16x4 __attribute__((ext_vector_type(4)));
typedef float  f32x4  __attribute__((ext_vector_type(4)));

__device__ __forceinline__ f32x4 mfma16(bf16x8 a, bf16x8 b, f32x4 c) {
    return __builtin_amdgcn_mfma_f32_16x16x32_bf16(a, b, c, 0, 0, 0);
}

__device__ __forceinline__ float fexp2(float x) {
#if __has_builtin(__builtin_amdgcn_exp2f)
    return __builtin_amdgcn_exp2f(x);
#else
    return exp2f(x);
#endif
}

// ---------------- Phase 0a: mask dtype probe ----------------
__global__ __launch_bounds__(256) void mask_probe(const unsigned char* __restrict__ m,
                                                  int* __restrict__ flag) {
    int nbytes = BATCH * NSEQ;
    int stride = gridDim.x * blockDim.x;
    int acc = 0;
    for (int i = blockIdx.x * blockDim.x + threadIdx.x; i < nbytes; i += stride)
        if ((i & 3) && m[i]) acc = 1;
    if (__any(acc)) {
        if ((threadIdx.x & 63) == 0) atomicOr(flag, 1);
    }
}

// ---------------- Phase 0b: expand mask to additive fp32 [B][NPAD] ----------------
__global__ __launch_bounds__(256) void mask_expand(const void* __restrict__ mraw,
                                                   const int* __restrict__ flag,
                                                   float* __restrict__ mask_f) {
    int t = blockIdx.x * blockDim.x + threadIdx.x;
    if (t >= BATCH * NPAD) return;
    int b = t / NPAD, k = t - b * NPAD;
    bool masked;
    if (k >= NSEQ) masked = true;
    else if (*flag) masked = ((const unsigned char*)mraw)[b * NSEQ + k] != 0;
    else            masked = ((const int*)mraw)[b * NSEQ + k] != 0;
    mask_f[t] = masked ? -1e30f : 0.f;
}

// ---------------- Phase 0c: bias_build — bias[h][q][k] = rpb[h][rel[q][k]] * log2e ----------------
__global__ __launch_bounds__(256) void bias_build(
    const int* __restrict__ rel, const float* __restrict__ rpb,
    bf16_t* __restrict__ bias, int num_rel) {
    __shared__ float rpb_s[NRELCAP];
    int h = blockIdx.y;
    const float* rph = rpb + (size_t)h * num_rel;
    int nr = num_rel > NRELCAP ? NRELCAP : num_rel;
    for (int i = threadIdx.x; i < nr; i += 256) rpb_s[i] = rph[i] * LOG2E;
    __syncthreads();
    int q0 = blockIdx.x * 32;
    int qend = q0 + 32 > NSEQ ? NSEQ : q0 + 32;
    for (int q = q0; q < qend; ++q) {
        bf16_t* brow = bias + ((size_t)h * NSEQ + q) * NPAD;
        const int* rrow = rel + (size_t)q * NSEQ;
        for (int k4 = threadIdx.x * 4; k4 < NPAD; k4 += 1024) {
            bf16x4 w;
            #pragma unroll
            for (int j = 0; j < 4; ++j) {
                int k = k4 + j;
                float v = (k < NSEQ) ? rpb_s[rrow[k]] : -1e30f;
                w[j] = (bf16_t)v;
            }
            *(bf16x4*)&brow[k4] = w;
        }
    }
}

// ---------------- Phase 1: fp32 -> bf16 casts ----------------
__global__ __launch_bounds__(256) void convert_kernel(
    const float* __restrict__ x, const float* __restrict__ wq, const float* __restrict__ wp,
    bf16_t* __restrict__ xb, bf16_t* __restrict__ wqb, bf16_t* __restrict__ wpb) {
    const int NX4 = MTOK*DMODEL/4, NQ4 = 768*256/4, NP4 = 256*256/4;
    int stride = gridDim.x * blockDim.x;
    int tid = blockIdx.x * blockDim.x + threadIdx.x;
    for (int i = tid; i < NX4; i += stride) {
        float4 f = ((const float4*)x)[i];
        bf16x4 o = { (bf16_t)f.x, (bf16_t)f.y, (bf16_t)f.z, (bf16_t)f.w };
        ((bf16x4*)xb)[i] = o;
    }
    for (int i = tid; i < NQ4; i += stride) {
        float4 f = ((const float4*)wq)[i];
        bf16x4 o = { (bf16_t)f.x, (bf16_t)f.y, (bf16_t)f.z, (bf16_t)f.w };
        ((bf16x4*)wqb)[i] = o;
    }
    for (int i = tid; i < NP4; i += stride) {
        float4 f = ((const float4*)wp)[i];
        bf16x4 o = { (bf16_t)f.x, (bf16_t)f.y, (bf16_t)f.z, (bf16_t)f.w };
        ((bf16x4*)wpb)[i] = o;
    }
}

// ---------------- Shared GEMM core (128x128 tile, BK=32, 4 waves) ----------------
#define GEMM_CORE(Aptr, Bptr) \
    __shared__ bf16_t As[128*32]; \
    __shared__ bf16_t Bs[128*32]; \
    int t = threadIdx.x; \
    int rowA0 = blockIdx.x * 128, rowB0 = blockIdx.y * 128; \
    int lane = t & 63, w = t >> 6; \
    int wr = (w >> 1) * 64, wc = (w & 1) * 64; \
    int lr = lane & 15, lg = lane >> 4; \
    int srow = t >> 2, scol = (t & 3) * 8; \
    f32x4 acc[4][4]; \
    { f32x4 zz = {0.f,0.f,0.f,0.f}; \
      _Pragma("unroll") for (int m = 0; m < 4; ++m) \
      _Pragma("unroll") for (int n = 0; n < 4; ++n) acc[m][n] = zz; } \
    for (int k0 = 0; k0 < 256; k0 += 32) { \
        bf16x8 ra0 = *(const bf16x8*)&Aptr[(size_t)(rowA0 + srow) * 256 + k0 + scol]; \
        bf16x8 ra1 = *(const bf16x8*)&Aptr[(size_t)(rowA0 + 64 + srow) * 256 + k0 + scol]; \
        bf16x8 rb0 = *(const bf16x8*)&Bptr[(size_t)(rowB0 + srow) * 256 + k0 + scol]; \
        bf16x8 rb1 = *(const bf16x8*)&Bptr[(size_t)(rowB0 + 64 + srow) * 256 + k0 + scol]; \
        __syncthreads(); \
        *(bf16x8*)&As[srow * 32 + scol] = ra0; \
        *(bf16x8*)&As[(64 + srow) * 32 + scol] = ra1; \
        *(bf16x8*)&Bs[srow * 32 + scol] = rb0; \
        *(bf16x8*)&Bs[(64 + srow) * 32 + scol] = rb1; \
        __syncthreads(); \
        bf16x8 af[4], bfr[4]; \
        _Pragma("unroll") for (int m = 0; m < 4; ++m) \
            af[m] = *(const bf16x8*)&As[(wr + m * 16 + lr) * 32 + lg * 8]; \
        _Pragma("unroll") for (int n = 0; n < 4; ++n) \
            bfr[n] = *(const bf16x8*)&Bs[(wc + n * 16 + lr) * 32 + lg * 8]; \
        _Pragma("unroll") for (int m = 0; m < 4; ++m) \
        _Pragma("unroll") for (int n = 0; n < 4; ++n) \
            acc[m][n] = mfma16(af[m], bfr[n], acc[m][n]); \
    }

// ---------------- Phase 2: QKV GEMM with q/k/vt scatter epilogue ----------------
__global__ __launch_bounds__(256) void gemm_qkv(
    const bf16_t* __restrict__ A, const bf16_t* __restrict__ Bw,
    bf16_t* __restrict__ qb, bf16_t* __restrict__ kb, bf16_t* __restrict__ vt) {
    GEMM_CORE(A, Bw)
    #pragma unroll
    for (int m = 0; m < 4; ++m) {
        #pragma unroll
        for (int i = 0; i < 4; ++i) {
            int grow = rowA0 + wr + m * 16 + lg * 4 + i;   // global token
            int b = grow / NSEQ, nt = grow - b * NSEQ;
            #pragma unroll
            for (int n = 0; n < 4; ++n) {
                int col = rowB0 + wc + n * 16 + lr;        // 0..767
                int which = col >> 8, hh = (col >> 5) & 7, d = col & 31;
                float v = acc[m][n][i];
                size_t hoff = (size_t)(b * NH + hh);
                if (which == 0) {
                    qb[(hoff * NPAD + nt) * DH + d] = (bf16_t)(v * QSCALE_L2);
                } else if (which == 1) {
                    kb[(hoff * NPAD + nt) * DH + d] = (bf16_t)v;
                } else {
                    vt[(hoff * DH + d) * NPAD + nt] = (bf16_t)v;
                }
            }
        }
    }
}

// ---------------- Phase 4: proj GEMM + bias ----------------
__global__ __launch_bounds__(256) void gemm_proj(
    const bf16_t* __restrict__ A, const bf16_t* __restrict__ Bw,
    const float* __restrict__ bias, float* __restrict__ out) {
    GEMM_CORE(A, Bw)
    #pragma unroll
    for (int m = 0; m < 4; ++m) {
        #pragma unroll
        for (int i = 0; i < 4; ++i) {
            int grow = rowA0 + wr + m * 16 + lg * 4 + i;
            #pragma unroll
            for (int n = 0; n < 4; ++n) {
                int col = rowB0 + wc + n * 16 + lr;        // 0..255
                out[(size_t)grow * DMODEL + col] = acc[m][n][i] + bias[col];
            }
        }
    }
}

// ---------------- Phase 3: fused flash attention (pipelined, exp2 domain) ----------------
// grid (19, 8, 16): (qtile, head, batch); 4 waves x 16 q-rows; 32 keys/iter.
// Swapped mfma(K,Q): lane owns q=qbase+lr; s0[i] key kbase+4lg+i, s1[i] key +16.
// PV for tile kt-1 runs at iter kt (P double-buffered in LDS) so the
// ds_write->ds_read gap spans a full iteration. Next-tile K/bias/mask and
// current-tile V prefetched into regs. Scores are in log2 domain (scale*log2e
// folded into Q at gemm_qkv; bias prescaled by log2e).
__global__ __launch_bounds__(256) void attn_kernel(
    const bf16_t* __restrict__ qb, const bf16_t* __restrict__ kb, const bf16_t* __restrict__ vt,
    const bf16_t* __restrict__ bias, const float* __restrict__ mask_f,
    bf16_t* __restrict__ att) {
    __shared__ __align__(16) bf16_t P[2][4][16][40];   // double-buffered, 80B row stride
    int t = threadIdx.x;
    int h = blockIdx.y, b = blockIdx.z;
    int lane = t & 63, wid = t >> 6;
    int qbase = blockIdx.x * 64 + wid * 16;
    if (qbase >= NSEQ) return;                          // no __syncthreads in kernel
    int lr = lane & 15, lg = lane >> 4;

    const bf16_t* qh = qb + (size_t)(b * NH + h) * NPAD * DH;
    const bf16_t* kh = kb + (size_t)(b * NH + h) * NPAD * DH;
    const bf16_t* vh = vt + (size_t)(b * NH + h) * DH * NPAD;
    const bf16_t* bh = bias + ((size_t)h * NSEQ + qbase + lr) * NPAD;  // this lane's q-row
    const float*  mh = mask_f + b * NPAD;

    bf16x8 qf = *(const bf16x8*)&qh[(qbase + lr) * DH + lg * 8];
    f32x4 o0 = {0.f,0.f,0.f,0.f}, o1 = {0.f,0.f,0.f,0.f};
    float mrow = -3e38f, lpart = 0.f;

    // preload tile 0
    bf16x8 kf0 = *(const bf16x8*)&kh[lr * DH + lg * 8];
    bf16x8 kf1 = *(const bf16x8*)&kh[(16 + lr) * DH + lg * 8];
    bf16x4 bv0 = *(const bf16x4*)&bh[4 * lg];
    bf16x4 bv1 = *(const bf16x4*)&bh[16 + 4 * lg];
    f32x4 m0 = *(const f32x4*)&mh[4 * lg];
    f32x4 m1 = *(const f32x4*)&mh[16 + 4 * lg];
    bf16x8 vf0, vf1;

    const int NT = NPAD / 32;   // 37
    for (int kt = 0; kt < NT; ++kt) {
        int kbase = kt * 32;
        int nb = (kt + 1 < NT) ? kbase + 32 : kbase;   // clamp: harmless reload on last iter
        // ---- prefetch: next K/bias/mask, current V (consumed next iter) ----
        bf16x8 nkf0 = *(const bf16x8*)&kh[(nb + lr) * DH + lg * 8];
        bf16x8 nkf1 = *(const bf16x8*)&kh[(nb + 16 + lr) * DH + lg * 8];
        bf16x4 nbv0 = *(const bf16x4*)&bh[nb + 4 * lg];
        bf16x4 nbv1 = *(const bf16x4*)&bh[nb + 16 + 4 * lg];
        f32x4 nm0 = *(const f32x4*)&mh[nb + 4 * lg];
        f32x4 nm1 = *(const f32x4*)&mh[nb + 16 + 4 * lg];
        bf16x8 nvf0 = *(const bf16x8*)&vh[(size_t)lr * NPAD + kbase + lg * 8];
        bf16x8 nvf1 = *(const bf16x8*)&vh[(size_t)(16 + lr) * NPAD + kbase + lg * 8];

        // ---- scores for tile kt ----
        f32x4 z = {0.f,0.f,0.f,0.f};
        __builtin_amdgcn_s_setprio(1);
        f32x4 s0 = mfma16(kf0, qf, z);   // s0[i]: key=kbase+4lg+i, q=qbase+lr
        f32x4 s1 = mfma16(kf1, qf, z);
        __builtin_amdgcn_s_setprio(0);
        #pragma unroll
        for (int i = 0; i < 4; ++i) {
            s0[i] += (float)bv0[i] + m0[i];
            s1[i] += (float)bv1[i] + m1[i];
        }

        // ---- delayed PV for tile kt-1 (P and o both consistent with old mrow) ----
        if (kt) {
            bf16x8 pf = *(const bf16x8*)&P[(kt - 1) & 1][wid][lr][lg * 8];
            __builtin_amdgcn_s_setprio(1);
            o0 = mfma16(pf, vf0, o0);
            o1 = mfma16(pf, vf1, o1);
            __builtin_amdgcn_s_setprio(0);
        }

        // ---- online softmax (defer-max, log2 domain) ----
        float pmax = fmaxf(fmaxf(fmaxf(s0[0], s0[1]), fmaxf(s0[2], s0[3])),
                           fmaxf(fmaxf(s1[0], s1[1]), fmaxf(s1[2], s1[3])));
        if (!__all(pmax - mrow <= 8.f)) {
            float fm = fmaxf(pmax, __shfl_xor(pmax, 16));
            fm = fmaxf(fm, __shfl_xor(fm, 32));
            float mn = fmaxf(mrow, fm);
            float al = fexp2(mrow - mn);
            mrow = mn;
            lpart *= al;
            #pragma unroll
            for (int i = 0; i < 4; ++i) {
                float ali = __shfl(al, (lane & 48) | (4 * lg + i), 64);
                o0[i] *= ali; o1[i] *= ali;
            }
        }
        f32x4 p0, p1;
        #pragma unroll
        for (int i = 0; i < 4; ++i) {
            p0[i] = fexp2(s0[i] - mrow);
            p1[i] = fexp2(s1[i] - mrow);
        }
        lpart += p0[0] + p0[1] + p0[2] + p0[3] + p1[0] + p1[1] + p1[2] + p1[3];
        bf16x4 w0 = { (bf16_t)p0[0], (bf16_t)p0[1], (bf16_t)p0[2], (bf16_t)p0[3] };
        bf16x4 w1 = { (bf16_t)p1[0], (bf16_t)p1[1], (bf16_t)p1[2], (bf16_t)p1[3] };
        *(bf16x4*)&P[kt & 1][wid][lr][4 * lg] = w0;
        *(bf16x4*)&P[kt & 1][wid][lr][16 + 4 * lg] = w1;

        // ---- rotate pipeline regs ----
        kf0 = nkf0; kf1 = nkf1; bv0 = nbv0; bv1 = nbv1;
        m0 = nm0; m1 = nm1; vf0 = nvf0; vf1 = nvf1;
    }
    // epilogue: PV for last tile
    {
        bf16x8 pf = *(const bf16x8*)&P[(NT - 1) & 1][wid][lr][lg * 8];
        o0 = mfma16(pf, vf0, o0);
        o1 = mfma16(pf, vf1, o1);
    }
    // full row-sum (2 shfl) + per-output-row redistribution
    float l = lpart + __shfl_xor(lpart, 16);
    l += __shfl_xor(l, 32);
    float linv = 1.f / l;                          // valid for q=lr in every lane
    #pragma unroll
    for (int i = 0; i < 4; ++i) {
        float li = __shfl(linv, (lane & 48) | (4 * lg + i), 64);
        int qi = qbase + 4 * lg + i;
        size_t base = ((size_t)b * NSEQ + qi) * DMODEL + h * DH;
        att[base + lr] = (bf16_t)(o0[i] * li);
        att[base + 16 + lr] = (bf16_t)(o1[i] * li);
    }
}

// ---------------- launcher ----------------
extern "C" void kernel_launch(void* const* d_in, const int* in_sizes, int n_in,
                              void* d_out, int out_size, void* d_ws, size_t ws_size,
                              hipStream_t stream) {
    const float* x      = (const float*)d_in[0];
    const void*  mask   = d_in[1];
    const float* w_qkv  = (const float*)d_in[2];
    const float* w_proj = (const float*)d_in[3];
    const float* b_proj = (const float*)d_in[4];
    const float* rpb    = (const float*)d_in[5];
    const int*   rel    = (const int*)d_in[6];
    float* out = (float*)d_out;
    int num_rel = in_sizes[5] / NH;

    char* ws = (char*)d_ws;
    bf16_t* xb   = (bf16_t*)(ws + 0);          // 9,568,256
    bf16_t* wqb  = (bf16_t*)(ws + 9568256);    // 393,216
    bf16_t* wpb  = (bf16_t*)(ws + 9961472);    // 131,072
    bf16_t* qb   = (bf16_t*)(ws + 10092544);   // 9,699,328
    bf16_t* kb   = (bf16_t*)(ws + 19791872);   // 9,699,328
    bf16_t* vt   = (bf16_t*)(ws + 29491200);   // 9,699,328
    bf16_t* att  = (bf16_t*)(ws + 39190528);   // 9,568,256
    float*  mask_fp = (float*)(ws + 48758784); // 75,776
    int*    flag    = (int*)(ws + 48834560);   // 64 (padded)
    bf16_t* bias = (bf16_t*)(ws + 48834624);   // 8*1168*1184*2 = 22,126,592 -> end 70,961,216

    hipMemsetAsync(flag, 0, 4, stream);
    mask_probe<<<dim3(32), dim3(256), 0, stream>>>((const unsigned char*)mask, flag);
    mask_expand<<<dim3((BATCH * NPAD + 255) / 256), dim3(256), 0, stream>>>(mask, flag, mask_fp);
    bias_build<<<dim3((NSEQ + 31) / 32, NH), dim3(256), 0, stream>>>(rel, rpb, bias, num_rel);
    convert_kernel<<<dim3(2048), dim3(256), 0, stream>>>(x, w_qkv, w_proj, xb, wqb, wpb);
    gemm_qkv<<<dim3(146, 6), dim3(256), 0, stream>>>(xb, wqb, qb, kb, vt);
    attn_kernel<<<dim3(19, NH, BATCH), dim3(256), 0, stream>>>(qb, kb, vt, bias, mask_fp, att);
    gemm_proj<<<dim3(146, 2), dim3(256), 0, stream>>>(att, wpb, b_proj, out);
}

// Round 6
// 277.969 us; speedup vs baseline: 1.1937x; 1.1937x over previous
//
#include <hip/hip_runtime.h>
#include <hip/hip_bf16.h>

// Problem constants
#define BATCH 16
#define NH 8
#define NSEQ 1168          // 12*12 + 32*32
#define NPAD 1184          // NSEQ padded to multiple of 32
#define DH 32
#define DMODEL 256
#define MTOK (BATCH*NSEQ)  // 18688 = 146*128
#define LOG2E 1.4426950408889634f
#define QSCALE_L2 (0.17677669529663687f * 1.4426950408889634f)  // 32^-0.5 * log2e
#define NRELCAP 8448       // num_rel = 8196 expected

typedef __bf16 bf16_t;
typedef __bf16 bf16x8 __attribute__((ext_vector_type(8)));
typedef __bf16 bf16x4 __attribute__((ext_vector_type(4)));
typedef __bf16 bf16x2 __attribute__((ext_vector_type(2)));
typedef float  f32x4  __attribute__((ext_vector_type(4)));

__device__ __forceinline__ f32x4 mfma16(bf16x8 a, bf16x8 b, f32x4 c) {
    return __builtin_amdgcn_mfma_f32_16x16x32_bf16(a, b, c, 0, 0, 0);
}

__device__ __forceinline__ float fexp2(float x) {
#if __has_builtin(__builtin_amdgcn_exp2f)
    return __builtin_amdgcn_exp2f(x);
#else
    return exp2f(x);
#endif
}

// ---------------- Phase 0a: mask dtype probe ----------------
__global__ __launch_bounds__(256) void mask_probe(const unsigned char* __restrict__ m,
                                                  int* __restrict__ flag) {
    int nbytes = BATCH * NSEQ;
    int stride = gridDim.x * blockDim.x;
    int acc = 0;
    for (int i = blockIdx.x * blockDim.x + threadIdx.x; i < nbytes; i += stride)
        if ((i & 3) && m[i]) acc = 1;
    if (__any(acc)) {
        if ((threadIdx.x & 63) == 0) atomicOr(flag, 1);
    }
}

// ---------------- Phase 0b: expand mask to additive fp32 [B][NPAD] ----------------
__global__ __launch_bounds__(256) void mask_expand(const void* __restrict__ mraw,
                                                   const int* __restrict__ flag,
                                                   float* __restrict__ mask_f) {
    int t = blockIdx.x * blockDim.x + threadIdx.x;
    if (t >= BATCH * NPAD) return;
    int b = t / NPAD, k = t - b * NPAD;
    bool masked;
    if (k >= NSEQ) masked = true;
    else if (*flag) masked = ((const unsigned char*)mraw)[b * NSEQ + k] != 0;
    else            masked = ((const int*)mraw)[b * NSEQ + k] != 0;
    mask_f[t] = masked ? -1e30f : 0.f;
}

// ---------------- Phase 0c: bias_build — bias[h][q][k] = rpb[h][rel[q][k]] * log2e ----------------
__global__ __launch_bounds__(256) void bias_build(
    const int* __restrict__ rel, const float* __restrict__ rpb,
    bf16_t* __restrict__ bias, int num_rel) {
    __shared__ float rpb_s[NRELCAP];
    int h = blockIdx.y;
    const float* rph = rpb + (size_t)h * num_rel;
    int nr = num_rel > NRELCAP ? NRELCAP : num_rel;
    for (int i = threadIdx.x; i < nr; i += 256) rpb_s[i] = rph[i] * LOG2E;
    __syncthreads();
    int q0 = blockIdx.x * 32;
    int qend = q0 + 32 > NSEQ ? NSEQ : q0 + 32;
    for (int q = q0; q < qend; ++q) {
        bf16_t* brow = bias + ((size_t)h * NSEQ + q) * NPAD;
        const int* rrow = rel + (size_t)q * NSEQ;
        for (int k4 = threadIdx.x * 4; k4 < NPAD; k4 += 1024) {
            bf16x4 w;
            if (k4 + 3 < NSEQ) {                       // int4-aligned fast path
                int4 r4 = *(const int4*)&rrow[k4];
                w[0] = (bf16_t)rpb_s[r4.x]; w[1] = (bf16_t)rpb_s[r4.y];
                w[2] = (bf16_t)rpb_s[r4.z]; w[3] = (bf16_t)rpb_s[r4.w];
            } else {
                #pragma unroll
                for (int j = 0; j < 4; ++j) {
                    int k = k4 + j;
                    w[j] = (bf16_t)((k < NSEQ) ? rpb_s[rrow[k]] : -1e30f);
                }
            }
            *(bf16x4*)&brow[k4] = w;
        }
    }
}

// ---------------- Phase 1: fp32 -> bf16 casts ----------------
__global__ __launch_bounds__(256) void convert_kernel(
    const float* __restrict__ x, const float* __restrict__ wq, const float* __restrict__ wp,
    bf16_t* __restrict__ xb, bf16_t* __restrict__ wqb, bf16_t* __restrict__ wpb) {
    const int NX4 = MTOK*DMODEL/4, NQ4 = 768*256/4, NP4 = 256*256/4;
    int stride = gridDim.x * blockDim.x;
    int tid = blockIdx.x * blockDim.x + threadIdx.x;
    for (int i = tid; i < NX4; i += stride) {
        float4 f = ((const float4*)x)[i];
        bf16x4 o = { (bf16_t)f.x, (bf16_t)f.y, (bf16_t)f.z, (bf16_t)f.w };
        ((bf16x4*)xb)[i] = o;
    }
    for (int i = tid; i < NQ4; i += stride) {
        float4 f = ((const float4*)wq)[i];
        bf16x4 o = { (bf16_t)f.x, (bf16_t)f.y, (bf16_t)f.z, (bf16_t)f.w };
        ((bf16x4*)wqb)[i] = o;
    }
    for (int i = tid; i < NP4; i += stride) {
        float4 f = ((const float4*)wp)[i];
        bf16x4 o = { (bf16_t)f.x, (bf16_t)f.y, (bf16_t)f.z, (bf16_t)f.w };
        ((bf16x4*)wpb)[i] = o;
    }
}

// ---------------- Shared GEMM core (128x128 tile, BK=32, 4 waves) ----------------
#define GEMM_CORE(Aptr, Bptr) \
    __shared__ bf16_t As[128*32]; \
    __shared__ bf16_t Bs[128*32]; \
    int t = threadIdx.x; \
    int rowA0 = blockIdx.x * 128, rowB0 = blockIdx.y * 128; \
    int lane = t & 63, w = t >> 6; \
    int wr = (w >> 1) * 64, wc = (w & 1) * 64; \
    int lr = lane & 15, lg = lane >> 4; \
    int srow = t >> 2, scol = (t & 3) * 8; \
    f32x4 acc[4][4]; \
    { f32x4 zz = {0.f,0.f,0.f,0.f}; \
      _Pragma("unroll") for (int m = 0; m < 4; ++m) \
      _Pragma("unroll") for (int n = 0; n < 4; ++n) acc[m][n] = zz; } \
    for (int k0 = 0; k0 < 256; k0 += 32) { \
        bf16x8 ra0 = *(const bf16x8*)&Aptr[(size_t)(rowA0 + srow) * 256 + k0 + scol]; \
        bf16x8 ra1 = *(const bf16x8*)&Aptr[(size_t)(rowA0 + 64 + srow) * 256 + k0 + scol]; \
        bf16x8 rb0 = *(const bf16x8*)&Bptr[(size_t)(rowB0 + srow) * 256 + k0 + scol]; \
        bf16x8 rb1 = *(const bf16x8*)&Bptr[(size_t)(rowB0 + 64 + srow) * 256 + k0 + scol]; \
        __syncthreads(); \
        *(bf16x8*)&As[srow * 32 + scol] = ra0; \
        *(bf16x8*)&As[(64 + srow) * 32 + scol] = ra1; \
        *(bf16x8*)&Bs[srow * 32 + scol] = rb0; \
        *(bf16x8*)&Bs[(64 + srow) * 32 + scol] = rb1; \
        __syncthreads(); \
        bf16x8 af[4], bfr[4]; \
        _Pragma("unroll") for (int m = 0; m < 4; ++m) \
            af[m] = *(const bf16x8*)&As[(wr + m * 16 + lr) * 32 + lg * 8]; \
        _Pragma("unroll") for (int n = 0; n < 4; ++n) \
            bfr[n] = *(const bf16x8*)&Bs[(wc + n * 16 + lr) * 32 + lg * 8]; \
        _Pragma("unroll") for (int m = 0; m < 4; ++m) \
        _Pragma("unroll") for (int n = 0; n < 4; ++n) \
            acc[m][n] = mfma16(af[m], bfr[n], acc[m][n]); \
    }

// ---------------- Phase 2: QKV GEMM with q/k scatter + LDS-transposed vt epilogue ----------------
__global__ __launch_bounds__(256) void gemm_qkv(
    const bf16_t* __restrict__ A, const bf16_t* __restrict__ Bw,
    bf16_t* __restrict__ qb, bf16_t* __restrict__ kb, bf16_t* __restrict__ vt) {
    __shared__ bf16_t TT[128][130];   // stride 130 elems (65 words): col reads are 2-way banks (free)
    GEMM_CORE(A, Bw)
    if (rowB0 < 512) {
        // q/k epilogue: 2B stores, 16 consecutive lanes contiguous (32B runs)
        #pragma unroll
        for (int m = 0; m < 4; ++m) {
            #pragma unroll
            for (int i = 0; i < 4; ++i) {
                int grow = rowA0 + wr + m * 16 + lg * 4 + i;
                int b = grow / NSEQ, nt = grow - b * NSEQ;
                #pragma unroll
                for (int n = 0; n < 4; ++n) {
                    int col = rowB0 + wc + n * 16 + lr;        // 0..511
                    int hh = (col >> 5) & 7, d = col & 31;
                    float v = acc[m][n][i];
                    size_t hoff = (size_t)(b * NH + hh);
                    if (col < 256) qb[(hoff * NPAD + nt) * DH + d] = (bf16_t)(v * QSCALE_L2);
                    else           kb[(hoff * NPAD + nt) * DH + d] = (bf16_t)v;
                }
            }
        }
    } else {
        // vt epilogue: restage in LDS, write [d][token] coalesced (4B/lane runs)
        #pragma unroll
        for (int m = 0; m < 4; ++m)
            #pragma unroll
            for (int i = 0; i < 4; ++i)
                #pragma unroll
                for (int n = 0; n < 4; ++n)
                    TT[wr + m * 16 + lg * 4 + i][wc + n * 16 + lr] = (bf16_t)acc[m][n][i];
        __syncthreads();
        int grow0 = rowA0 + 2 * lane;            // NSEQ even => token pair same batch
        int b = grow0 / NSEQ, nt = grow0 - b * NSEQ;
        for (int cc = 0; cc < 32; ++cc) {
            int col = rowB0 + w * 32 + cc;       // 512..767
            int hh = (col >> 5) & 7, d = col & 31;
            bf16x2 v = { TT[2 * lane][w * 32 + cc], TT[2 * lane + 1][w * 32 + cc] };
            *(bf16x2*)&vt[((size_t)(b * NH + hh) * DH + d) * NPAD + nt] = v;
        }
    }
}

// ---------------- Phase 4: proj GEMM + bias ----------------
__global__ __launch_bounds__(256) void gemm_proj(
    const bf16_t* __restrict__ A, const bf16_t* __restrict__ Bw,
    const float* __restrict__ bias, float* __restrict__ out) {
    GEMM_CORE(A, Bw)
    #pragma unroll
    for (int m = 0; m < 4; ++m) {
        #pragma unroll
        for (int i = 0; i < 4; ++i) {
            int grow = rowA0 + wr + m * 16 + lg * 4 + i;
            #pragma unroll
            for (int n = 0; n < 4; ++n) {
                int col = rowB0 + wc + n * 16 + lr;        // 0..255
                out[(size_t)grow * DMODEL + col] = acc[m][n][i] + bias[col];
            }
        }
    }
}

// ---------------- Phase 3: fused flash attention (R4 structure, exp2, XCD-swizzled) ----------------
// 1D grid 2432; decode so all 16 batches of one (h,qtile) pair land on XCD p%8.
// Swapped mfma(K,Q): lane owns q=qbase+lr; s0[i] key kbase+4lg+i, s1[i] key +16.
__global__ __launch_bounds__(256) void attn_kernel(
    const bf16_t* __restrict__ qb, const bf16_t* __restrict__ kb, const bf16_t* __restrict__ vt,
    const bf16_t* __restrict__ bias, const float* __restrict__ mask_f,
    bf16_t* __restrict__ att) {
    __shared__ __align__(16) float mask_s[NPAD];
    __shared__ __align__(16) bf16_t P[4][16][40];   // 80B row: 2-way banks on b128 read (free)
    int t = threadIdx.x;
    // XCD-aware decode (assumes round-robin linear-id -> XCD)
    int f = blockIdx.x;
    int xcd = f & 7, j = f >> 3;
    int p = xcd + 8 * (j % 19);     // pair 0..151; p % 8 == xcd for every batch
    int b = j / 19;                 // 0..15
    int qt = p % 19, h = p / 19;

    for (int k = t; k < NPAD; k += 256) mask_s[k] = mask_f[b * NPAD + k];
    __syncthreads();

    int lane = t & 63, wid = t >> 6;
    int qbase = qt * 64 + wid * 16;
    if (qbase >= NSEQ) return;
    int lr = lane & 15, lg = lane >> 4;

    const bf16_t* qh = qb + (size_t)(b * NH + h) * NPAD * DH;
    const bf16_t* kh = kb + (size_t)(b * NH + h) * NPAD * DH;
    const bf16_t* vh = vt + (size_t)(b * NH + h) * DH * NPAD;
    const bf16_t* bh = bias + ((size_t)h * NSEQ + qbase + lr) * NPAD;  // this lane's q-row

    bf16x8 qf = *(const bf16x8*)&qh[(qbase + lr) * DH + lg * 8];
    f32x4 o0 = {0.f,0.f,0.f,0.f}, o1 = {0.f,0.f,0.f,0.f};
    float mrow = -3e38f, lpart = 0.f;

    for (int kt = 0; kt < NPAD / 32; ++kt) {
        int kbase = kt * 32;
        bf16x8 kf0 = *(const bf16x8*)&kh[(kbase + lr) * DH + lg * 8];
        bf16x8 kf1 = *(const bf16x8*)&kh[(kbase + 16 + lr) * DH + lg * 8];
        bf16x4 bv0 = *(const bf16x4*)&bh[kbase + 4 * lg];
        bf16x4 bv1 = *(const bf16x4*)&bh[kbase + 16 + 4 * lg];
        // V for this tile: issued early, consumed after the P round-trip
        bf16x8 vf0 = *(const bf16x8*)&vh[(size_t)lr * NPAD + kbase + lg * 8];
        bf16x8 vf1 = *(const bf16x8*)&vh[(size_t)(16 + lr) * NPAD + kbase + lg * 8];
        f32x4 m0 = *(const f32x4*)&mask_s[kbase + 4 * lg];
        f32x4 m1 = *(const f32x4*)&mask_s[kbase + 16 + 4 * lg];
        f32x4 z = {0.f,0.f,0.f,0.f};
        __builtin_amdgcn_s_setprio(1);
        f32x4 s0 = mfma16(kf0, qf, z);   // s0[i]: key=kbase+4lg+i, q=qbase+lr
        f32x4 s1 = mfma16(kf1, qf, z);
        __builtin_amdgcn_s_setprio(0);
        #pragma unroll
        for (int i = 0; i < 4; ++i) {
            s0[i] += (float)bv0[i] + m0[i];
            s1[i] += (float)bv1[i] + m1[i];
        }
        float pmax = fmaxf(fmaxf(fmaxf(s0[0], s0[1]), fmaxf(s0[2], s0[3])),
                           fmaxf(fmaxf(s1[0], s1[1]), fmaxf(s1[2], s1[3])));
        if (!__all(pmax - mrow <= 8.f)) {          // defer-max: rare path
            float fm = fmaxf(pmax, __shfl_xor(pmax, 16));
            fm = fmaxf(fm, __shfl_xor(fm, 32));
            float mn = fmaxf(mrow, fm);
            float al = fexp2(mrow - mn);
            mrow = mn;
            lpart *= al;
            #pragma unroll
            for (int i = 0; i < 4; ++i) {
                float ali = __shfl(al, (lane & 48) | (4 * lg + i), 64);
                o0[i] *= ali; o1[i] *= ali;
            }
        }
        f32x4 p0, p1;
        #pragma unroll
        for (int i = 0; i < 4; ++i) {
            p0[i] = fexp2(s0[i] - mrow);
            p1[i] = fexp2(s1[i] - mrow);
        }
        lpart += p0[0] + p0[1] + p0[2] + p0[3] + p1[0] + p1[1] + p1[2] + p1[3];
        bf16x4 w0 = { (bf16_t)p0[0], (bf16_t)p0[1], (bf16_t)p0[2], (bf16_t)p0[3] };
        bf16x4 w1 = { (bf16_t)p1[0], (bf16_t)p1[1], (bf16_t)p1[2], (bf16_t)p1[3] };
        *(bf16x4*)&P[wid][lr][4 * lg] = w0;        // keys 4lg..4lg+3 contiguous
        *(bf16x4*)&P[wid][lr][16 + 4 * lg] = w1;
        asm volatile("s_waitcnt lgkmcnt(0)" ::: "memory");
        bf16x8 pf = *(const bf16x8*)&P[wid][lr][lg * 8];                    // A-frag P[q][k]
        __builtin_amdgcn_s_setprio(1);
        o0 = mfma16(pf, vf0, o0);
        o1 = mfma16(pf, vf1, o1);
        __builtin_amdgcn_s_setprio(0);
    }
    // epilogue: full row-sum (2 shfl) + per-output-row redistribution
    float l = lpart + __shfl_xor(lpart, 16);
    l += __shfl_xor(l, 32);
    float linv = 1.f / l;                          // valid for q=lr in every lane
    #pragma unroll
    for (int i = 0; i < 4; ++i) {
        float li = __shfl(linv, (lane & 48) | (4 * lg + i), 64);
        int qi = qbase + 4 * lg + i;
        size_t base = ((size_t)b * NSEQ + qi) * DMODEL + h * DH;
        att[base + lr] = (bf16_t)(o0[i] * li);
        att[base + 16 + lr] = (bf16_t)(o1[i] * li);
    }
}

// ---------------- launcher ----------------
extern "C" void kernel_launch(void* const* d_in, const int* in_sizes, int n_in,
                              void* d_out, int out_size, void* d_ws, size_t ws_size,
                              hipStream_t stream) {
    const float* x      = (const float*)d_in[0];
    const void*  mask   = d_in[1];
    const float* w_qkv  = (const float*)d_in[2];
    const float* w_proj = (const float*)d_in[3];
    const float* b_proj = (const float*)d_in[4];
    const float* rpb    = (const float*)d_in[5];
    const int*   rel    = (const int*)d_in[6];
    float* out = (float*)d_out;
    int num_rel = in_sizes[5] / NH;

    char* ws = (char*)d_ws;
    bf16_t* xb   = (bf16_t*)(ws + 0);          // 9,568,256
    bf16_t* wqb  = (bf16_t*)(ws + 9568256);    // 393,216
    bf16_t* wpb  = (bf16_t*)(ws + 9961472);    // 131,072
    bf16_t* qb   = (bf16_t*)(ws + 10092544);   // 9,699,328
    bf16_t* kb   = (bf16_t*)(ws + 19791872);   // 9,699,328
    bf16_t* vt   = (bf16_t*)(ws + 29491200);   // 9,699,328
    bf16_t* att  = (bf16_t*)(ws + 39190528);   // 9,568,256
    float*  mask_fp = (float*)(ws + 48758784); // 75,776
    int*    flag    = (int*)(ws + 48834560);   // 64 (padded)
    bf16_t* bias = (bf16_t*)(ws + 48834624);   // 22,126,592 -> end 70,961,216

    hipMemsetAsync(flag, 0, 4, stream);
    mask_probe<<<dim3(32), dim3(256), 0, stream>>>((const unsigned char*)mask, flag);
    mask_expand<<<dim3((BATCH * NPAD + 255) / 256), dim3(256), 0, stream>>>(mask, flag, mask_fp);
    bias_build<<<dim3((NSEQ + 31) / 32, NH), dim3(256), 0, stream>>>(rel, rpb, bias, num_rel);
    convert_kernel<<<dim3(2048), dim3(256), 0, stream>>>(x, w_qkv, w_proj, xb, wqb, wpb);
    gemm_qkv<<<dim3(146, 6), dim3(256), 0, stream>>>(xb, wqb, qb, kb, vt);
    attn_kernel<<<dim3(19 * NH * BATCH), dim3(256), 0, stream>>>(qb, kb, vt, bias, mask_fp, att);
    gemm_proj<<<dim3(146, 2), dim3(256), 0, stream>>>(att, wpb, b_proj, out);
}